// Round 14
// baseline (406.743 us; speedup 1.0000x reference)
//
#include <hip/hip_runtime.h>
#include <hip/hip_bf16.h>

// GCN: h1 = relu(Â (x W1) + b1); h2 = relu(Â (h1 W2) + b2);
// out = mean_pool(h2, batch) @ Wlin + blin,  Â = D^-1/2 (A+I) D^-1/2
//
// R2: per-graph counts via sorted-batch boundaries.
// R3: norm folded into gemm epilogue (xws = dinv*xw).
// R5/R6: bucketed CSR build, deterministic two-pass, zero global atomics.
// R7: xws bf16 -> agg row gather 128 B.
// R8/R9 LESSON: sub-dword per-lane global stores defeat L2 write-merge.
// R10: agg v2 -- 2 edges per gather instr (instruction-bound, not byte-bound).
// R11/R13: aggpool fusion kept; W2-gemm fusion rejected.
// R12 LESSON: multi-node gather unroll spills to scratch. One context/wave.
// R14: gemm v4 -- 64x64 tile, 4x4 micro-tile/thread, k-vectorized b128 LDS
//     reads for BOTH W and X (LDS-instr count /4; gemm was LDS-bound ~45us).
//     aggpool v2 -- barrier-free: wave atomics its row directly (the
//     __syncthreads max-degree tail cost ~33us; atomic chains cost ~8us).

#define NDIM 64
#define NGRAPH 64
#define BSHIFT 7                      // 128 nodes per bucket
#define BNODES 128
#define ECHUNK 8192                   // edges per block in bincnt/bscatter (32/thread)

__device__ __forceinline__ unsigned short f32_to_bf16(float f) {
    unsigned int u = __float_as_uint(f);
    unsigned int r = 0x7FFFu + ((u >> 16) & 1u);   // round-to-nearest-even
    return (unsigned short)((u + r) >> 16);
}

// ---- pass 1: per-(block,bucket) edge counts via LDS histogram ----
__global__ void bincnt_k(const int* __restrict__ dst, int* __restrict__ cntmat,
                         int e, int nb) {
    extern __shared__ int hist[];
    int t = threadIdx.x;
    for (int i = t; i < nb; i += 256) hist[i] = 0;
    __syncthreads();
    int base = blockIdx.x * ECHUNK + t;
#pragma unroll
    for (int k = 0; k < 32; ++k) {
        int i = base + k * 256;
        if (i < e) atomicAdd(&hist[dst[i] >> BSHIFT], 1);   // LDS atomic
    }
    __syncthreads();
    long row = (long)blockIdx.x * nb;
    for (int i = t; i < nb; i += 256) cntmat[row + i] = hist[i];
}

// ---- pass 2: per-bucket exclusive scan across blocks (one block per bucket) ----
__global__ void colscan_k(const int* __restrict__ cntmat, int* __restrict__ basemat,
                          int* __restrict__ bucketTot, int nblk, int nb) {
    __shared__ int s[256];
    int b = blockIdx.x;
    int t = threadIdx.x;
    int v = (t < nblk) ? cntmat[(long)t * nb + b] : 0;
    s[t] = v;
    __syncthreads();
    for (int off = 1; off < 256; off <<= 1) {
        int tmp = (t >= off) ? s[t - off] : 0;
        __syncthreads();
        s[t] += tmp;
        __syncthreads();
    }
    if (t < nblk) basemat[(long)t * nb + b] = s[t] - v;   // exclusive within column
    if (t == 255) bucketTot[b] = s[255];
}

// ---- pass 3: exclusive scan of bucket totals (single block, nb<=1024) ----
__global__ void bscan_k(const int* __restrict__ bucketTot, int* __restrict__ bucketStart,
                        int* __restrict__ start, int nb, int n, int e) {
    __shared__ int s[1024];
    int t = threadIdx.x;
    int v = (t < nb) ? bucketTot[t] : 0;
    s[t] = v;
    __syncthreads();
    for (int off = 1; off < 1024; off <<= 1) {
        int tmp = (t >= off) ? s[t - off] : 0;
        __syncthreads();
        s[t] += tmp;
        __syncthreads();
    }
    if (t < nb) bucketStart[t + 1] = s[t];
    if (t == 0) { bucketStart[0] = 0; start[n] = e; }   // CSR sentinel
}

// ---- pass 4: scatter packed (dst_local<<25 | src) via block-private LDS cursors ----
__global__ void bscatter_k(const int* __restrict__ src, const int* __restrict__ dst,
                           const int* __restrict__ bucketStart,
                           const int* __restrict__ basemat,
                           unsigned int* __restrict__ ebuf, int e, int nb) {
    extern __shared__ int cur[];
    int t = threadIdx.x;
    long row = (long)blockIdx.x * nb;
    for (int i = t; i < nb; i += 256) cur[i] = bucketStart[i] + basemat[row + i];
    __syncthreads();
    int base = blockIdx.x * ECHUNK + t;
#pragma unroll
    for (int k = 0; k < 32; ++k) {
        int i = base + k * 256;
        if (i < e) {
            int d = dst[i];
            int b = d >> BSHIFT;
            int pos = atomicAdd(&cur[b], 1);               // LDS atomic, block-private
            ebuf[pos] = ((unsigned)(d & (BNODES - 1)) << 25) | (unsigned)src[i];
        }
    }
}

// ---- pass 5: one block per bucket -> dst-ordered CSR slice, dinv, graph ranges ----
__global__ void fill2_k(const unsigned int* __restrict__ ebuf,
                        const int* __restrict__ bucketStart,
                        const int* __restrict__ batch, float* __restrict__ dinv,
                        int* __restrict__ start, int* __restrict__ csr,
                        int* __restrict__ gstart, int* __restrict__ gend, int n) {
    __shared__ int scnt[BNODES], sincl[BNODES], scur[BNODES];
    int t = threadIdx.x;
    int b = blockIdx.x;
    int node0 = b << BSHIFT;
    int nNodes = min(BNODES, n - node0);
    if (t < BNODES) scnt[t] = 0;
    int e0 = bucketStart[b], e1 = bucketStart[b + 1];
    __syncthreads();
    for (int i = e0 + t; i < e1; i += 256)
        atomicAdd(&scnt[ebuf[i] >> 25], 1);
    __syncthreads();
    int val = (t < BNODES) ? scnt[t] : 0;
    if (t < BNODES) sincl[t] = val;
    __syncthreads();
    for (int off = 1; off < BNODES; off <<= 1) {
        int tmp = (t >= off && t < BNODES) ? sincl[t - off] : 0;
        __syncthreads();
        if (t < BNODES) sincl[t] += tmp;
        __syncthreads();
    }
    if (t < nNodes) {
        int v = node0 + t;
        int st = e0 + sincl[t] - val;     // exclusive within bucket
        start[v] = st;
        scur[t] = st;
        dinv[v] = rsqrtf((float)(val + 1));
        int g = batch[v];                 // sorted-batch boundary detection
        if (v == 0 || batch[v - 1] != g) gstart[g] = v;
        if (v == n - 1 || batch[v + 1] != g) gend[g] = v + 1;
    }
    __syncthreads();
    for (int i = e0 + t; i < e1; i += 256) {
        unsigned rec = ebuf[i];
        int pos = atomicAdd(&scur[rec >> 25], 1);
        csr[pos] = (int)(rec & 0x1FFFFFFu);   // scatter within L2-local 8 KB slice
    }
}

// ---- dense GEMM v4  C[n,64](bf16 pairs) = scale[row] * (A[n,64] @ W[64,64]) ----
// 64x64 tile/block; thread (rg=t>>4, cg=t&15) computes rows 4rg..+3, cols 4cg..+3.
// Inner loop over k4: b128 LDS reads for W (4) and X (4) -> 16 FMAs x 4 k.
// All named locals (no addressable aggregates). Stores: 8 B/lane dwordx2.
__global__ void gemm_k(const float* __restrict__ A, const float* __restrict__ W,
                       const float* __restrict__ scale,
                       unsigned long long* __restrict__ C, int n) {
    __shared__ float4 Wl4[64 * 16];   // 16 KB: W[k][4c..4c+3]
    __shared__ float4 Xl4[64 * 16];   // 16 KB: X[r][4k..4k+3]
    int t = threadIdx.x;
    const float4* W4 = (const float4*)W;
#pragma unroll
    for (int i = 0; i < 4; ++i) Wl4[t + 256 * i] = W4[t + 256 * i];
    const float4* A4 = (const float4*)A;
    long fbase = (long)blockIdx.x * 1024;
    long fmax  = (long)n * 16;
#pragma unroll
    for (int i = 0; i < 4; ++i) {
        long f = fbase + t + 256 * i;
        float4 v;
        if (f < fmax) v = A4[f];
        else { v.x = 0.f; v.y = 0.f; v.z = 0.f; v.w = 0.f; }
        Xl4[t + 256 * i] = v;
    }
    __syncthreads();
    int rg = t >> 4, cg = t & 15;
    float a00 = 0.f, a01 = 0.f, a02 = 0.f, a03 = 0.f;
    float a10 = 0.f, a11 = 0.f, a12 = 0.f, a13 = 0.f;
    float a20 = 0.f, a21 = 0.f, a22 = 0.f, a23 = 0.f;
    float a30 = 0.f, a31 = 0.f, a32 = 0.f, a33 = 0.f;
#pragma unroll 4
    for (int k4 = 0; k4 < 16; ++k4) {
        float4 w0 = Wl4[(4 * k4 + 0) * 16 + cg];
        float4 w1 = Wl4[(4 * k4 + 1) * 16 + cg];
        float4 w2 = Wl4[(4 * k4 + 2) * 16 + cg];
        float4 w3 = Wl4[(4 * k4 + 3) * 16 + cg];
        float4 x0 = Xl4[(4 * rg + 0) * 16 + k4];
        float4 x1 = Xl4[(4 * rg + 1) * 16 + k4];
        float4 x2 = Xl4[(4 * rg + 2) * 16 + k4];
        float4 x3 = Xl4[(4 * rg + 3) * 16 + k4];
        a00 += x0.x * w0.x + x0.y * w1.x + x0.z * w2.x + x0.w * w3.x;
        a01 += x0.x * w0.y + x0.y * w1.y + x0.z * w2.y + x0.w * w3.y;
        a02 += x0.x * w0.z + x0.y * w1.z + x0.z * w2.z + x0.w * w3.z;
        a03 += x0.x * w0.w + x0.y * w1.w + x0.z * w2.w + x0.w * w3.w;
        a10 += x1.x * w0.x + x1.y * w1.x + x1.z * w2.x + x1.w * w3.x;
        a11 += x1.x * w0.y + x1.y * w1.y + x1.z * w2.y + x1.w * w3.y;
        a12 += x1.x * w0.z + x1.y * w1.z + x1.z * w2.z + x1.w * w3.z;
        a13 += x1.x * w0.w + x1.y * w1.w + x1.z * w2.w + x1.w * w3.w;
        a20 += x2.x * w0.x + x2.y * w1.x + x2.z * w2.x + x2.w * w3.x;
        a21 += x2.x * w0.y + x2.y * w1.y + x2.z * w2.y + x2.w * w3.y;
        a22 += x2.x * w0.z + x2.y * w1.z + x2.z * w2.z + x2.w * w3.z;
        a23 += x2.x * w0.w + x2.y * w1.w + x2.z * w2.w + x2.w * w3.w;
        a30 += x3.x * w0.x + x3.y * w1.x + x3.z * w2.x + x3.w * w3.x;
        a31 += x3.x * w0.y + x3.y * w1.y + x3.z * w2.y + x3.w * w3.y;
        a32 += x3.x * w0.z + x3.y * w1.z + x3.z * w2.z + x3.w * w3.z;
        a33 += x3.x * w0.w + x3.y * w1.w + x3.z * w2.w + x3.w * w3.w;
    }
    int vb = blockIdx.x * 64 + rg * 4;
    int v;
    float s;
    unsigned long long u;
    v = vb + 0;
    if (v < n) {
        s = scale[v];
        u  = (unsigned long long)(((unsigned int)f32_to_bf16(s * a01) << 16) | (unsigned int)f32_to_bf16(s * a00));
        u |= (unsigned long long)(((unsigned int)f32_to_bf16(s * a03) << 16) | (unsigned int)f32_to_bf16(s * a02)) << 32;
        C[(long)v * 16 + cg] = u;
    }
    v = vb + 1;
    if (v < n) {
        s = scale[v];
        u  = (unsigned long long)(((unsigned int)f32_to_bf16(s * a11) << 16) | (unsigned int)f32_to_bf16(s * a10));
        u |= (unsigned long long)(((unsigned int)f32_to_bf16(s * a13) << 16) | (unsigned int)f32_to_bf16(s * a12)) << 32;
        C[(long)v * 16 + cg] = u;
    }
    v = vb + 2;
    if (v < n) {
        s = scale[v];
        u  = (unsigned long long)(((unsigned int)f32_to_bf16(s * a21) << 16) | (unsigned int)f32_to_bf16(s * a20));
        u |= (unsigned long long)(((unsigned int)f32_to_bf16(s * a23) << 16) | (unsigned int)f32_to_bf16(s * a22)) << 32;
        C[(long)v * 16 + cg] = u;
    }
    v = vb + 3;
    if (v < n) {
        s = scale[v];
        u  = (unsigned long long)(((unsigned int)f32_to_bf16(s * a31) << 16) | (unsigned int)f32_to_bf16(s * a30));
        u |= (unsigned long long)(((unsigned int)f32_to_bf16(s * a33) << 16) | (unsigned int)f32_to_bf16(s * a32)) << 32;
        C[(long)v * 16 + cg] = u;
    }
}

// ---- gather core (R10-proven): 2 edges per gather instruction ----
// lane covers dim pair p=lane&31 via dword (2 bf16); half-wave h=lane>>5
// handles edges i+h. Returns value for dim d = 2p+h (self-loop included).
__device__ __forceinline__ float gather_row(const unsigned int* __restrict__ xp,
                                            const int* __restrict__ csr,
                                            int s0, int d0, int h, int p, int v) {
    float l0 = 0.f, l1 = 0.f, l2 = 0.f, l3 = 0.f;
    float h0 = 0.f, h1 = 0.f, h2 = 0.f, h3 = 0.f;
    int i = 0;
    for (; i + 8 <= d0; i += 8) {
        int j0 = csr[s0 + i + 0 + h];
        int j1 = csr[s0 + i + 2 + h];
        int j2 = csr[s0 + i + 4 + h];
        int j3 = csr[s0 + i + 6 + h];
        unsigned int u0 = xp[(long)j0 * 32 + p];
        unsigned int u1 = xp[(long)j1 * 32 + p];
        unsigned int u2 = xp[(long)j2 * 32 + p];
        unsigned int u3 = xp[(long)j3 * 32 + p];
        l0 += __uint_as_float(u0 << 16);  h0 += __uint_as_float(u0 & 0xFFFF0000u);
        l1 += __uint_as_float(u1 << 16);  h1 += __uint_as_float(u1 & 0xFFFF0000u);
        l2 += __uint_as_float(u2 << 16);  h2 += __uint_as_float(u2 & 0xFFFF0000u);
        l3 += __uint_as_float(u3 << 16);  h3 += __uint_as_float(u3 & 0xFFFF0000u);
    }
    for (; i + 2 <= d0; i += 2) {
        int j = csr[s0 + i + h];
        unsigned int u = xp[(long)j * 32 + p];
        l0 += __uint_as_float(u << 16);
        h0 += __uint_as_float(u & 0xFFFF0000u);
    }
    if (i < d0 && h == 0) {               // odd leftover edge: half-wave 0 only
        int j = csr[s0 + i];
        unsigned int u = xp[(long)j * 32 + p];
        l0 += __uint_as_float(u << 16);
        h0 += __uint_as_float(u & 0xFFFF0000u);
    }
    float al = (l0 + l1) + (l2 + l3);
    float ah = (h0 + h1) + (h2 + h3);
    al += __shfl_xor(al, 32);             // merge the two half-waves
    ah += __shfl_xor(ah, 32);
    unsigned int us = xp[(long)v * 32 + p];   // self loop
    al += __uint_as_float(us << 16);
    ah += __uint_as_float(us & 0xFFFF0000u);
    return h ? ah : al;
}

// ---- aggregation (layer 1): out[v,:] = relu( dinv[v]*gather + b ), f32 out ----
__global__ void agg_k(const unsigned int* __restrict__ xp, const float* __restrict__ dinv,
                      const int* __restrict__ start, const int* __restrict__ csr,
                      const float* __restrict__ bias, float* __restrict__ out, int n) {
    int t = threadIdx.x;
    int lane = t & 63;
    int h = lane >> 5;
    int p = lane & 31;
    int v = blockIdx.x * 4 + (t >> 6);
    if (v >= n) return;
    int s0 = start[v];
    int d0 = start[v + 1] - s0;
    float sum = gather_row(xp, csr, s0, d0, h, p, v);
    int d = 2 * p + h;
    float val = sum * dinv[v] + bias[d];
    out[(long)v * NDIM + d] = fmaxf(val, 0.f);
}

// ---- fused layer2-agg + mean-pool, barrier-free: wave atomics its row ----
__global__ void aggpool_k(const unsigned int* __restrict__ xp, const float* __restrict__ dinv,
                          const int* __restrict__ start, const int* __restrict__ csr,
                          const float* __restrict__ b2, const int* __restrict__ batch,
                          float* __restrict__ pooled, int n) {
    int t = threadIdx.x;
    int lane = t & 63;
    int h = lane >> 5, p = lane & 31;
    int v = blockIdx.x * 4 + (t >> 6);
    if (v >= n) return;
    int s0 = start[v];
    int d0 = start[v + 1] - s0;
    float sum = gather_row(xp, csr, s0, d0, h, p, v);
    int d = 2 * p + h;
    float val = fmaxf(sum * dinv[v] + b2[d], 0.f);
    atomicAdd(&pooled[batch[v] * NDIM + d], val);   // 64 consecutive dwords/wave
}

// ---- head: out[g,c] = (pooled[g,:]/max(cnt,1)) @ Wlin + blin ----
__global__ void final_k(const float* __restrict__ pooled, const int* __restrict__ gstart,
                        const int* __restrict__ gend,
                        const float* __restrict__ Wlin, const float* __restrict__ blin,
                        float* __restrict__ out, int nclass) {
    int t = blockIdx.x * blockDim.x + threadIdx.x;
    if (t >= NGRAPH * nclass) return;
    int g = t / nclass, c = t % nclass;
    float cnt = (float)(gend[g] - gstart[g]);
    float inv = 1.f / fmaxf(cnt, 1.f);
    float acc = 0.f;
    for (int j = 0; j < NDIM; ++j) acc += pooled[g * NDIM + j] * Wlin[j * nclass + c];
    out[t] = acc * inv + blin[c];
}

extern "C" void kernel_launch(void* const* d_in, const int* in_sizes, int n_in,
                              void* d_out, int out_size, void* d_ws, size_t ws_size,
                              hipStream_t stream) {
    const float* x     = (const float*)d_in[0];
    const int*   ei    = (const int*)d_in[1];
    const int*   batch = (const int*)d_in[2];
    const float* W1    = (const float*)d_in[3];
    const float* b1    = (const float*)d_in[4];
    const float* W2    = (const float*)d_in[5];
    const float* b2    = (const float*)d_in[6];
    const float* Wlin  = (const float*)d_in[7];
    const float* blin  = (const float*)d_in[8];
    float* out = (float*)d_out;

    const int N = in_sizes[0] / NDIM;        // 100000
    const int E = in_sizes[1] / 2;           // 1600000
    const int NCLASS = in_sizes[7] / NDIM;   // 10
    const int* src = ei;
    const int* dst = ei + E;
    const int NB   = (N + BNODES - 1) >> BSHIFT;        // 782 buckets (<=1024)
    const int NBLK = (E + ECHUNK - 1) / ECHUNK;         // 196 edge blocks (<=256)

    // ---- workspace carve-out (each 256B-aligned) ----
    size_t o = 0;
    char* wsp = (char*)d_ws;
    auto take = [&](size_t nbytes) -> void* {
        void* p = (void*)(wsp + o);
        o += (nbytes + 255) & ~(size_t)255;
        return p;
    };
    int*   gstart    = (int*)take(NGRAPH * 4);
    int*   gend      = (int*)take(NGRAPH * 4);
    float* pooled    = (float*)take(NGRAPH * NDIM * 4);
    size_t zero_bytes = o;                    // everything above must start at 0
    int*   cntmat   = (int*)take((size_t)NBLK * NB * 4);
    int*   basemat  = (int*)take((size_t)NBLK * NB * 4);
    int*   bucketTot   = (int*)take((size_t)NB * 4);
    int*   bucketStart = (int*)take((size_t)(NB + 1) * 4);
    float* dinv  = (float*)take((size_t)N * 4);
    int*   start = (int*)take((size_t)(N + 1) * 4);
    int*   csr   = (int*)take((size_t)E * 4);
    unsigned int* ebuf = (unsigned int*)take((size_t)E * 4);
    unsigned int* xws  = (unsigned int*)take((size_t)N * NDIM * 2);   // bf16 pairs
    float* h     = (float*)take((size_t)N * NDIM * 4);
    (void)ws_size;

    hipMemsetAsync(d_ws, 0, zero_bytes, stream);

    int rbl = (N + 3) / 4;                    // 4 nodes per block (agg/aggpool)
    int gbl = (N + 63) / 64;                  // 64 rows per block (gemm v4)

    // CSR build (deterministic two-pass binning, zero global atomics)
    bincnt_k<<<NBLK, 256, (size_t)NB * 4, stream>>>(dst, cntmat, E, NB);
    colscan_k<<<NB, 256, 0, stream>>>(cntmat, basemat, bucketTot, NBLK, NB);
    bscan_k<<<1, 1024, 0, stream>>>(bucketTot, bucketStart, start, NB, N, E);
    bscatter_k<<<NBLK, 256, (size_t)NB * 4, stream>>>(src, dst, bucketStart, basemat, ebuf, E, NB);
    fill2_k<<<NB, 256, 0, stream>>>(ebuf, bucketStart, batch, dinv, start, csr, gstart, gend, N);

    // layer 1
    gemm_k<<<gbl, 256, 0, stream>>>(x, W1, dinv, (unsigned long long*)xws, N);
    agg_k<<<rbl, 256, 0, stream>>>(xws, dinv, start, csr, b1, h, N);
    // layer 2
    gemm_k<<<gbl, 256, 0, stream>>>(h, W2, dinv, (unsigned long long*)xws, N);
    // fused layer2-agg + mean-pool (barrier-free)
    aggpool_k<<<rbl, 256, 0, stream>>>(xws, dinv, start, csr, b2, batch, pooled, N);
    // head
    final_k<<<(NGRAPH * NCLASS + 255) / 256, 256, 0, stream>>>(pooled, gstart, gend, Wlin, blin, out, NCLASS);
}

// Round 15
// 321.085 us; speedup vs baseline: 1.2668x; 1.2668x over previous
//
#include <hip/hip_runtime.h>
#include <hip/hip_bf16.h>

// GCN: h1 = relu(Â (x W1) + b1); h2 = relu(Â (h1 W2) + b2);
// out = mean_pool(h2, batch) @ Wlin + blin,  Â = D^-1/2 (A+I) D^-1/2
//
// R2: per-graph counts via sorted-batch boundaries.
// R5/R6: bucketed CSR build, deterministic two-pass, zero global atomics.
// R7: xws bf16 -> agg row gather 128 B.
// R8/R9 LESSON: sub-dword per-lane global stores defeat L2 write-merge.
// R10: agg v2 -- 2 edges per gather instr (instruction-bound).
// R12 LESSON: multi-node gather unroll spills to scratch. One context/wave.
// R14 LESSON: same-address global atomic chains ~125 ns/link; 1560-deep
//     chains cost ~195 us. Keep chain depth <= ~100.
// R15: aggpool v3 -- wave processes a contiguous ~25-node chunk, accumulates
//     the pooled row in registers (batch sorted), flushes on graph change /
//     chunk end: ~4160 row-atomics total, ~65-deep chains, no barrier.
//     gemm v4 (64x64 tile, 4x4 micro-tile, b128 LDS reads) kept from R14.

#define NDIM 64
#define NGRAPH 64
#define BSHIFT 7                      // 128 nodes per bucket
#define BNODES 128
#define ECHUNK 8192                   // edges per block in bincnt/bscatter (32/thread)

__device__ __forceinline__ unsigned short f32_to_bf16(float f) {
    unsigned int u = __float_as_uint(f);
    unsigned int r = 0x7FFFu + ((u >> 16) & 1u);   // round-to-nearest-even
    return (unsigned short)((u + r) >> 16);
}

// ---- pass 1: per-(block,bucket) edge counts via LDS histogram ----
__global__ void bincnt_k(const int* __restrict__ dst, int* __restrict__ cntmat,
                         int e, int nb) {
    extern __shared__ int hist[];
    int t = threadIdx.x;
    for (int i = t; i < nb; i += 256) hist[i] = 0;
    __syncthreads();
    int base = blockIdx.x * ECHUNK + t;
#pragma unroll
    for (int k = 0; k < 32; ++k) {
        int i = base + k * 256;
        if (i < e) atomicAdd(&hist[dst[i] >> BSHIFT], 1);   // LDS atomic
    }
    __syncthreads();
    long row = (long)blockIdx.x * nb;
    for (int i = t; i < nb; i += 256) cntmat[row + i] = hist[i];
}

// ---- pass 2: per-bucket exclusive scan across blocks (one block per bucket) ----
__global__ void colscan_k(const int* __restrict__ cntmat, int* __restrict__ basemat,
                          int* __restrict__ bucketTot, int nblk, int nb) {
    __shared__ int s[256];
    int b = blockIdx.x;
    int t = threadIdx.x;
    int v = (t < nblk) ? cntmat[(long)t * nb + b] : 0;
    s[t] = v;
    __syncthreads();
    for (int off = 1; off < 256; off <<= 1) {
        int tmp = (t >= off) ? s[t - off] : 0;
        __syncthreads();
        s[t] += tmp;
        __syncthreads();
    }
    if (t < nblk) basemat[(long)t * nb + b] = s[t] - v;   // exclusive within column
    if (t == 255) bucketTot[b] = s[255];
}

// ---- pass 3: exclusive scan of bucket totals (single block, nb<=1024) ----
__global__ void bscan_k(const int* __restrict__ bucketTot, int* __restrict__ bucketStart,
                        int* __restrict__ start, int nb, int n, int e) {
    __shared__ int s[1024];
    int t = threadIdx.x;
    int v = (t < nb) ? bucketTot[t] : 0;
    s[t] = v;
    __syncthreads();
    for (int off = 1; off < 1024; off <<= 1) {
        int tmp = (t >= off) ? s[t - off] : 0;
        __syncthreads();
        s[t] += tmp;
        __syncthreads();
    }
    if (t < nb) bucketStart[t + 1] = s[t];
    if (t == 0) { bucketStart[0] = 0; start[n] = e; }   // CSR sentinel
}

// ---- pass 4: scatter packed (dst_local<<25 | src) via block-private LDS cursors ----
__global__ void bscatter_k(const int* __restrict__ src, const int* __restrict__ dst,
                           const int* __restrict__ bucketStart,
                           const int* __restrict__ basemat,
                           unsigned int* __restrict__ ebuf, int e, int nb) {
    extern __shared__ int cur[];
    int t = threadIdx.x;
    long row = (long)blockIdx.x * nb;
    for (int i = t; i < nb; i += 256) cur[i] = bucketStart[i] + basemat[row + i];
    __syncthreads();
    int base = blockIdx.x * ECHUNK + t;
#pragma unroll
    for (int k = 0; k < 32; ++k) {
        int i = base + k * 256;
        if (i < e) {
            int d = dst[i];
            int b = d >> BSHIFT;
            int pos = atomicAdd(&cur[b], 1);               // LDS atomic, block-private
            ebuf[pos] = ((unsigned)(d & (BNODES - 1)) << 25) | (unsigned)src[i];
        }
    }
}

// ---- pass 5: one block per bucket -> dst-ordered CSR slice, dinv, graph ranges ----
__global__ void fill2_k(const unsigned int* __restrict__ ebuf,
                        const int* __restrict__ bucketStart,
                        const int* __restrict__ batch, float* __restrict__ dinv,
                        int* __restrict__ start, int* __restrict__ csr,
                        int* __restrict__ gstart, int* __restrict__ gend, int n) {
    __shared__ int scnt[BNODES], sincl[BNODES], scur[BNODES];
    int t = threadIdx.x;
    int b = blockIdx.x;
    int node0 = b << BSHIFT;
    int nNodes = min(BNODES, n - node0);
    if (t < BNODES) scnt[t] = 0;
    int e0 = bucketStart[b], e1 = bucketStart[b + 1];
    __syncthreads();
    for (int i = e0 + t; i < e1; i += 256)
        atomicAdd(&scnt[ebuf[i] >> 25], 1);
    __syncthreads();
    int val = (t < BNODES) ? scnt[t] : 0;
    if (t < BNODES) sincl[t] = val;
    __syncthreads();
    for (int off = 1; off < BNODES; off <<= 1) {
        int tmp = (t >= off && t < BNODES) ? sincl[t - off] : 0;
        __syncthreads();
        if (t < BNODES) sincl[t] += tmp;
        __syncthreads();
    }
    if (t < nNodes) {
        int v = node0 + t;
        int st = e0 + sincl[t] - val;     // exclusive within bucket
        start[v] = st;
        scur[t] = st;
        dinv[v] = rsqrtf((float)(val + 1));
        int g = batch[v];                 // sorted-batch boundary detection
        if (v == 0 || batch[v - 1] != g) gstart[g] = v;
        if (v == n - 1 || batch[v + 1] != g) gend[g] = v + 1;
    }
    __syncthreads();
    for (int i = e0 + t; i < e1; i += 256) {
        unsigned rec = ebuf[i];
        int pos = atomicAdd(&scur[rec >> 25], 1);
        csr[pos] = (int)(rec & 0x1FFFFFFu);   // scatter within L2-local 8 KB slice
    }
}

// ---- dense GEMM v4  C[n,64](bf16 pairs) = scale[row] * (A[n,64] @ W[64,64]) ----
// 64x64 tile/block; thread (rg=t>>4, cg=t&15) computes rows 4rg..+3, cols 4cg..+3.
__global__ void gemm_k(const float* __restrict__ A, const float* __restrict__ W,
                       const float* __restrict__ scale,
                       unsigned long long* __restrict__ C, int n) {
    __shared__ float4 Wl4[64 * 16];   // 16 KB: W[k][4c..4c+3]
    __shared__ float4 Xl4[64 * 16];   // 16 KB: X[r][4k..4k+3]
    int t = threadIdx.x;
    const float4* W4 = (const float4*)W;
#pragma unroll
    for (int i = 0; i < 4; ++i) Wl4[t + 256 * i] = W4[t + 256 * i];
    const float4* A4 = (const float4*)A;
    long fbase = (long)blockIdx.x * 1024;
    long fmax  = (long)n * 16;
#pragma unroll
    for (int i = 0; i < 4; ++i) {
        long f = fbase + t + 256 * i;
        float4 v;
        if (f < fmax) v = A4[f];
        else { v.x = 0.f; v.y = 0.f; v.z = 0.f; v.w = 0.f; }
        Xl4[t + 256 * i] = v;
    }
    __syncthreads();
    int rg = t >> 4, cg = t & 15;
    float a00 = 0.f, a01 = 0.f, a02 = 0.f, a03 = 0.f;
    float a10 = 0.f, a11 = 0.f, a12 = 0.f, a13 = 0.f;
    float a20 = 0.f, a21 = 0.f, a22 = 0.f, a23 = 0.f;
    float a30 = 0.f, a31 = 0.f, a32 = 0.f, a33 = 0.f;
#pragma unroll 4
    for (int k4 = 0; k4 < 16; ++k4) {
        float4 w0 = Wl4[(4 * k4 + 0) * 16 + cg];
        float4 w1 = Wl4[(4 * k4 + 1) * 16 + cg];
        float4 w2 = Wl4[(4 * k4 + 2) * 16 + cg];
        float4 w3 = Wl4[(4 * k4 + 3) * 16 + cg];
        float4 x0 = Xl4[(4 * rg + 0) * 16 + k4];
        float4 x1 = Xl4[(4 * rg + 1) * 16 + k4];
        float4 x2 = Xl4[(4 * rg + 2) * 16 + k4];
        float4 x3 = Xl4[(4 * rg + 3) * 16 + k4];
        a00 += x0.x * w0.x + x0.y * w1.x + x0.z * w2.x + x0.w * w3.x;
        a01 += x0.x * w0.y + x0.y * w1.y + x0.z * w2.y + x0.w * w3.y;
        a02 += x0.x * w0.z + x0.y * w1.z + x0.z * w2.z + x0.w * w3.z;
        a03 += x0.x * w0.w + x0.y * w1.w + x0.z * w2.w + x0.w * w3.w;
        a10 += x1.x * w0.x + x1.y * w1.x + x1.z * w2.x + x1.w * w3.x;
        a11 += x1.x * w0.y + x1.y * w1.y + x1.z * w2.y + x1.w * w3.y;
        a12 += x1.x * w0.z + x1.y * w1.z + x1.z * w2.z + x1.w * w3.z;
        a13 += x1.x * w0.w + x1.y * w1.w + x1.z * w2.w + x1.w * w3.w;
        a20 += x2.x * w0.x + x2.y * w1.x + x2.z * w2.x + x2.w * w3.x;
        a21 += x2.x * w0.y + x2.y * w1.y + x2.z * w2.y + x2.w * w3.y;
        a22 += x2.x * w0.z + x2.y * w1.z + x2.z * w2.z + x2.w * w3.z;
        a23 += x2.x * w0.w + x2.y * w1.w + x2.z * w2.w + x2.w * w3.w;
        a30 += x3.x * w0.x + x3.y * w1.x + x3.z * w2.x + x3.w * w3.x;
        a31 += x3.x * w0.y + x3.y * w1.y + x3.z * w2.y + x3.w * w3.y;
        a32 += x3.x * w0.z + x3.y * w1.z + x3.z * w2.z + x3.w * w3.z;
        a33 += x3.x * w0.w + x3.y * w1.w + x3.z * w2.w + x3.w * w3.w;
    }
    int vb = blockIdx.x * 64 + rg * 4;
    int v;
    float s;
    unsigned long long u;
    v = vb + 0;
    if (v < n) {
        s = scale[v];
        u  = (unsigned long long)(((unsigned int)f32_to_bf16(s * a01) << 16) | (unsigned int)f32_to_bf16(s * a00));
        u |= (unsigned long long)(((unsigned int)f32_to_bf16(s * a03) << 16) | (unsigned int)f32_to_bf16(s * a02)) << 32;
        C[(long)v * 16 + cg] = u;
    }
    v = vb + 1;
    if (v < n) {
        s = scale[v];
        u  = (unsigned long long)(((unsigned int)f32_to_bf16(s * a11) << 16) | (unsigned int)f32_to_bf16(s * a10));
        u |= (unsigned long long)(((unsigned int)f32_to_bf16(s * a13) << 16) | (unsigned int)f32_to_bf16(s * a12)) << 32;
        C[(long)v * 16 + cg] = u;
    }
    v = vb + 2;
    if (v < n) {
        s = scale[v];
        u  = (unsigned long long)(((unsigned int)f32_to_bf16(s * a21) << 16) | (unsigned int)f32_to_bf16(s * a20));
        u |= (unsigned long long)(((unsigned int)f32_to_bf16(s * a23) << 16) | (unsigned int)f32_to_bf16(s * a22)) << 32;
        C[(long)v * 16 + cg] = u;
    }
    v = vb + 3;
    if (v < n) {
        s = scale[v];
        u  = (unsigned long long)(((unsigned int)f32_to_bf16(s * a31) << 16) | (unsigned int)f32_to_bf16(s * a30));
        u |= (unsigned long long)(((unsigned int)f32_to_bf16(s * a33) << 16) | (unsigned int)f32_to_bf16(s * a32)) << 32;
        C[(long)v * 16 + cg] = u;
    }
}

// ---- gather core (R10-proven): 2 edges per gather instruction ----
__device__ __forceinline__ float gather_row(const unsigned int* __restrict__ xp,
                                            const int* __restrict__ csr,
                                            int s0, int d0, int h, int p, int v) {
    float l0 = 0.f, l1 = 0.f, l2 = 0.f, l3 = 0.f;
    float h0 = 0.f, h1 = 0.f, h2 = 0.f, h3 = 0.f;
    int i = 0;
    for (; i + 8 <= d0; i += 8) {
        int j0 = csr[s0 + i + 0 + h];
        int j1 = csr[s0 + i + 2 + h];
        int j2 = csr[s0 + i + 4 + h];
        int j3 = csr[s0 + i + 6 + h];
        unsigned int u0 = xp[(long)j0 * 32 + p];
        unsigned int u1 = xp[(long)j1 * 32 + p];
        unsigned int u2 = xp[(long)j2 * 32 + p];
        unsigned int u3 = xp[(long)j3 * 32 + p];
        l0 += __uint_as_float(u0 << 16);  h0 += __uint_as_float(u0 & 0xFFFF0000u);
        l1 += __uint_as_float(u1 << 16);  h1 += __uint_as_float(u1 & 0xFFFF0000u);
        l2 += __uint_as_float(u2 << 16);  h2 += __uint_as_float(u2 & 0xFFFF0000u);
        l3 += __uint_as_float(u3 << 16);  h3 += __uint_as_float(u3 & 0xFFFF0000u);
    }
    for (; i + 2 <= d0; i += 2) {
        int j = csr[s0 + i + h];
        unsigned int u = xp[(long)j * 32 + p];
        l0 += __uint_as_float(u << 16);
        h0 += __uint_as_float(u & 0xFFFF0000u);
    }
    if (i < d0 && h == 0) {               // odd leftover edge: half-wave 0 only
        int j = csr[s0 + i];
        unsigned int u = xp[(long)j * 32 + p];
        l0 += __uint_as_float(u << 16);
        h0 += __uint_as_float(u & 0xFFFF0000u);
    }
    float al = (l0 + l1) + (l2 + l3);
    float ah = (h0 + h1) + (h2 + h3);
    al += __shfl_xor(al, 32);             // merge the two half-waves
    ah += __shfl_xor(ah, 32);
    unsigned int us = xp[(long)v * 32 + p];   // self loop
    al += __uint_as_float(us << 16);
    ah += __uint_as_float(us & 0xFFFF0000u);
    return h ? ah : al;
}

// ---- aggregation (layer 1): out[v,:] = relu( dinv[v]*gather + b ), f32 out ----
__global__ void agg_k(const unsigned int* __restrict__ xp, const float* __restrict__ dinv,
                      const int* __restrict__ start, const int* __restrict__ csr,
                      const float* __restrict__ bias, float* __restrict__ out, int n) {
    int t = threadIdx.x;
    int lane = t & 63;
    int h = lane >> 5;
    int p = lane & 31;
    int v = blockIdx.x * 4 + (t >> 6);
    if (v >= n) return;
    int s0 = start[v];
    int d0 = start[v + 1] - s0;
    float sum = gather_row(xp, csr, s0, d0, h, p, v);
    int d = 2 * p + h;
    float val = sum * dinv[v] + bias[d];
    out[(long)v * NDIM + d] = fmaxf(val, 0.f);
}

// ---- aggpool v3: wave processes a contiguous node chunk, accumulates the
// pooled row in registers (batch sorted), flushes on graph change/chunk end.
// ~4160 row-atomics total, ~65-deep chains, no barrier, no LDS.
__global__ void aggpool_k(const unsigned int* __restrict__ xp, const float* __restrict__ dinv,
                          const int* __restrict__ start, const int* __restrict__ csr,
                          const float* __restrict__ b2, const int* __restrict__ batch,
                          float* __restrict__ pooled, int n, int chunk) {
    int t = threadIdx.x;
    int lane = t & 63;
    int h = lane >> 5, p = lane & 31;
    int wid = blockIdx.x * 4 + (t >> 6);
    int v0 = wid * chunk;
    if (v0 >= n) return;
    int v1 = min(v0 + chunk, n);
    int d = 2 * p + h;
    float bias = b2[d];
    int gcur = -1;
    float acc = 0.f;
    for (int v = v0; v < v1; ++v) {
        int g = batch[v];                         // wave-uniform broadcast load
        if (g != gcur) {
            if (gcur >= 0) atomicAdd(&pooled[gcur * NDIM + d], acc);
            gcur = g;
            acc = 0.f;
        }
        int s0 = start[v];
        int d0 = start[v + 1] - s0;
        float sum = gather_row(xp, csr, s0, d0, h, p, v);
        acc += fmaxf(sum * dinv[v] + bias, 0.f);
    }
    if (gcur >= 0) atomicAdd(&pooled[gcur * NDIM + d], acc);
}

// ---- head: out[g,c] = (pooled[g,:]/max(cnt,1)) @ Wlin + blin ----
__global__ void final_k(const float* __restrict__ pooled, const int* __restrict__ gstart,
                        const int* __restrict__ gend,
                        const float* __restrict__ Wlin, const float* __restrict__ blin,
                        float* __restrict__ out, int nclass) {
    int t = blockIdx.x * blockDim.x + threadIdx.x;
    if (t >= NGRAPH * nclass) return;
    int g = t / nclass, c = t % nclass;
    float cnt = (float)(gend[g] - gstart[g]);
    float inv = 1.f / fmaxf(cnt, 1.f);
    float acc = 0.f;
    for (int j = 0; j < NDIM; ++j) acc += pooled[g * NDIM + j] * Wlin[j * nclass + c];
    out[t] = acc * inv + blin[c];
}

extern "C" void kernel_launch(void* const* d_in, const int* in_sizes, int n_in,
                              void* d_out, int out_size, void* d_ws, size_t ws_size,
                              hipStream_t stream) {
    const float* x     = (const float*)d_in[0];
    const int*   ei    = (const int*)d_in[1];
    const int*   batch = (const int*)d_in[2];
    const float* W1    = (const float*)d_in[3];
    const float* b1    = (const float*)d_in[4];
    const float* W2    = (const float*)d_in[5];
    const float* b2    = (const float*)d_in[6];
    const float* Wlin  = (const float*)d_in[7];
    const float* blin  = (const float*)d_in[8];
    float* out = (float*)d_out;

    const int N = in_sizes[0] / NDIM;        // 100000
    const int E = in_sizes[1] / 2;           // 1600000
    const int NCLASS = in_sizes[7] / NDIM;   // 10
    const int* src = ei;
    const int* dst = ei + E;
    const int NB   = (N + BNODES - 1) >> BSHIFT;        // 782 buckets (<=1024)
    const int NBLK = (E + ECHUNK - 1) / ECHUNK;         // 196 edge blocks (<=256)

    // ---- workspace carve-out (each 256B-aligned) ----
    size_t o = 0;
    char* wsp = (char*)d_ws;
    auto take = [&](size_t nbytes) -> void* {
        void* p = (void*)(wsp + o);
        o += (nbytes + 255) & ~(size_t)255;
        return p;
    };
    int*   gstart    = (int*)take(NGRAPH * 4);
    int*   gend      = (int*)take(NGRAPH * 4);
    float* pooled    = (float*)take(NGRAPH * NDIM * 4);
    size_t zero_bytes = o;                    // everything above must start at 0
    int*   cntmat   = (int*)take((size_t)NBLK * NB * 4);
    int*   basemat  = (int*)take((size_t)NBLK * NB * 4);
    int*   bucketTot   = (int*)take((size_t)NB * 4);
    int*   bucketStart = (int*)take((size_t)(NB + 1) * 4);
    float* dinv  = (float*)take((size_t)N * 4);
    int*   start = (int*)take((size_t)(N + 1) * 4);
    int*   csr   = (int*)take((size_t)E * 4);
    unsigned int* ebuf = (unsigned int*)take((size_t)E * 4);
    unsigned int* xws  = (unsigned int*)take((size_t)N * NDIM * 2);   // bf16 pairs
    float* h     = (float*)take((size_t)N * NDIM * 4);
    (void)ws_size;

    hipMemsetAsync(d_ws, 0, zero_bytes, stream);

    int rbl = (N + 3) / 4;                    // 4 nodes per block (agg)
    int gbl = (N + 63) / 64;                  // 64 rows per block (gemm v4)
    const int PBLK  = 1024;                   // aggpool blocks (4096 waves)
    const int CHUNK = (N + PBLK * 4 - 1) / (PBLK * 4);   // ~25 nodes/wave

    // CSR build (deterministic two-pass binning, zero global atomics)
    bincnt_k<<<NBLK, 256, (size_t)NB * 4, stream>>>(dst, cntmat, E, NB);
    colscan_k<<<NB, 256, 0, stream>>>(cntmat, basemat, bucketTot, NBLK, NB);
    bscan_k<<<1, 1024, 0, stream>>>(bucketTot, bucketStart, start, NB, N, E);
    bscatter_k<<<NBLK, 256, (size_t)NB * 4, stream>>>(src, dst, bucketStart, basemat, ebuf, E, NB);
    fill2_k<<<NB, 256, 0, stream>>>(ebuf, bucketStart, batch, dinv, start, csr, gstart, gend, N);

    // layer 1
    gemm_k<<<gbl, 256, 0, stream>>>(x, W1, dinv, (unsigned long long*)xws, N);
    agg_k<<<rbl, 256, 0, stream>>>(xws, dinv, start, csr, b1, h, N);
    // layer 2
    gemm_k<<<gbl, 256, 0, stream>>>(h, W2, dinv, (unsigned long long*)xws, N);
    // fused layer2-agg + chunked register mean-pool
    aggpool_k<<<PBLK, 256, 0, stream>>>(xws, dinv, start, csr, b2, batch, pooled, N, CHUNK);
    // head
    final_k<<<(NGRAPH * NCLASS + 255) / 256, 256, 0, stream>>>(pooled, gstart, gend, Wlin, blin, out, NCLASS);
}

// Round 16
// 295.573 us; speedup vs baseline: 1.3761x; 1.0863x over previous
//
#include <hip/hip_runtime.h>
#include <hip/hip_bf16.h>

// GCN: h1 = relu(Â (x W1) + b1); h2 = relu(Â (h1 W2) + b2);
// out = mean_pool(h2, batch) @ Wlin + blin,  Â = D^-1/2 (A+I) D^-1/2
//
// R5/R6: bucketed CSR build, deterministic two-pass, zero global atomics.
// R7: xws bf16 -> agg row gather 128 B.
// R8/R9 LESSON: sub-dword per-lane global stores defeat L2 write-merge.
// R10: agg v2 -- 2 edges per gather instr (instruction-bound).
// R12 LESSON: multi-node gather unroll spills to scratch. One context/wave.
// R14 LESSON: same-address global atomic chains ~125 ns/link; keep <= ~100.
// R15 LESSON: chunk=25 pooling starved occupancy (4096 waves, 37% occ, 90us).
// R16: aggpool v4 -- 32x replicated pooled accumulator (rep = wid&31)
//     decouples chain depth from wave count: chunk=4 -> 25000 waves
//     (occupancy ~68%) with ~12-deep chains. reduce_k folds replicas.

#define NDIM 64
#define NGRAPH 64
#define NREP 32
#define BSHIFT 7                      // 128 nodes per bucket
#define BNODES 128
#define ECHUNK 8192                   // edges per block in bincnt/bscatter (32/thread)

__device__ __forceinline__ unsigned short f32_to_bf16(float f) {
    unsigned int u = __float_as_uint(f);
    unsigned int r = 0x7FFFu + ((u >> 16) & 1u);   // round-to-nearest-even
    return (unsigned short)((u + r) >> 16);
}

// ---- pass 1: per-(block,bucket) edge counts via LDS histogram ----
__global__ void bincnt_k(const int* __restrict__ dst, int* __restrict__ cntmat,
                         int e, int nb) {
    extern __shared__ int hist[];
    int t = threadIdx.x;
    for (int i = t; i < nb; i += 256) hist[i] = 0;
    __syncthreads();
    int base = blockIdx.x * ECHUNK + t;
#pragma unroll
    for (int k = 0; k < 32; ++k) {
        int i = base + k * 256;
        if (i < e) atomicAdd(&hist[dst[i] >> BSHIFT], 1);   // LDS atomic
    }
    __syncthreads();
    long row = (long)blockIdx.x * nb;
    for (int i = t; i < nb; i += 256) cntmat[row + i] = hist[i];
}

// ---- pass 2: per-bucket exclusive scan across blocks (one block per bucket) ----
__global__ void colscan_k(const int* __restrict__ cntmat, int* __restrict__ basemat,
                          int* __restrict__ bucketTot, int nblk, int nb) {
    __shared__ int s[256];
    int b = blockIdx.x;
    int t = threadIdx.x;
    int v = (t < nblk) ? cntmat[(long)t * nb + b] : 0;
    s[t] = v;
    __syncthreads();
    for (int off = 1; off < 256; off <<= 1) {
        int tmp = (t >= off) ? s[t - off] : 0;
        __syncthreads();
        s[t] += tmp;
        __syncthreads();
    }
    if (t < nblk) basemat[(long)t * nb + b] = s[t] - v;   // exclusive within column
    if (t == 255) bucketTot[b] = s[255];
}

// ---- pass 3: exclusive scan of bucket totals (single block, nb<=1024) ----
__global__ void bscan_k(const int* __restrict__ bucketTot, int* __restrict__ bucketStart,
                        int* __restrict__ start, int nb, int n, int e) {
    __shared__ int s[1024];
    int t = threadIdx.x;
    int v = (t < nb) ? bucketTot[t] : 0;
    s[t] = v;
    __syncthreads();
    for (int off = 1; off < 1024; off <<= 1) {
        int tmp = (t >= off) ? s[t - off] : 0;
        __syncthreads();
        s[t] += tmp;
        __syncthreads();
    }
    if (t < nb) bucketStart[t + 1] = s[t];
    if (t == 0) { bucketStart[0] = 0; start[n] = e; }   // CSR sentinel
}

// ---- pass 4: scatter packed (dst_local<<25 | src) via block-private LDS cursors ----
__global__ void bscatter_k(const int* __restrict__ src, const int* __restrict__ dst,
                           const int* __restrict__ bucketStart,
                           const int* __restrict__ basemat,
                           unsigned int* __restrict__ ebuf, int e, int nb) {
    extern __shared__ int cur[];
    int t = threadIdx.x;
    long row = (long)blockIdx.x * nb;
    for (int i = t; i < nb; i += 256) cur[i] = bucketStart[i] + basemat[row + i];
    __syncthreads();
    int base = blockIdx.x * ECHUNK + t;
#pragma unroll
    for (int k = 0; k < 32; ++k) {
        int i = base + k * 256;
        if (i < e) {
            int d = dst[i];
            int b = d >> BSHIFT;
            int pos = atomicAdd(&cur[b], 1);               // LDS atomic, block-private
            ebuf[pos] = ((unsigned)(d & (BNODES - 1)) << 25) | (unsigned)src[i];
        }
    }
}

// ---- pass 5: one block per bucket -> dst-ordered CSR slice, dinv, graph ranges ----
__global__ void fill2_k(const unsigned int* __restrict__ ebuf,
                        const int* __restrict__ bucketStart,
                        const int* __restrict__ batch, float* __restrict__ dinv,
                        int* __restrict__ start, int* __restrict__ csr,
                        int* __restrict__ gstart, int* __restrict__ gend, int n) {
    __shared__ int scnt[BNODES], sincl[BNODES], scur[BNODES];
    int t = threadIdx.x;
    int b = blockIdx.x;
    int node0 = b << BSHIFT;
    int nNodes = min(BNODES, n - node0);
    if (t < BNODES) scnt[t] = 0;
    int e0 = bucketStart[b], e1 = bucketStart[b + 1];
    __syncthreads();
    for (int i = e0 + t; i < e1; i += 256)
        atomicAdd(&scnt[ebuf[i] >> 25], 1);
    __syncthreads();
    int val = (t < BNODES) ? scnt[t] : 0;
    if (t < BNODES) sincl[t] = val;
    __syncthreads();
    for (int off = 1; off < BNODES; off <<= 1) {
        int tmp = (t >= off && t < BNODES) ? sincl[t - off] : 0;
        __syncthreads();
        if (t < BNODES) sincl[t] += tmp;
        __syncthreads();
    }
    if (t < nNodes) {
        int v = node0 + t;
        int st = e0 + sincl[t] - val;     // exclusive within bucket
        start[v] = st;
        scur[t] = st;
        dinv[v] = rsqrtf((float)(val + 1));
        int g = batch[v];                 // sorted-batch boundary detection
        if (v == 0 || batch[v - 1] != g) gstart[g] = v;
        if (v == n - 1 || batch[v + 1] != g) gend[g] = v + 1;
    }
    __syncthreads();
    for (int i = e0 + t; i < e1; i += 256) {
        unsigned rec = ebuf[i];
        int pos = atomicAdd(&scur[rec >> 25], 1);
        csr[pos] = (int)(rec & 0x1FFFFFFu);   // scatter within L2-local 8 KB slice
    }
}

// ---- dense GEMM v4  C[n,64](bf16 pairs) = scale[row] * (A[n,64] @ W[64,64]) ----
__global__ void gemm_k(const float* __restrict__ A, const float* __restrict__ W,
                       const float* __restrict__ scale,
                       unsigned long long* __restrict__ C, int n) {
    __shared__ float4 Wl4[64 * 16];   // 16 KB: W[k][4c..4c+3]
    __shared__ float4 Xl4[64 * 16];   // 16 KB: X[r][4k..4k+3]
    int t = threadIdx.x;
    const float4* W4 = (const float4*)W;
#pragma unroll
    for (int i = 0; i < 4; ++i) Wl4[t + 256 * i] = W4[t + 256 * i];
    const float4* A4 = (const float4*)A;
    long fbase = (long)blockIdx.x * 1024;
    long fmax  = (long)n * 16;
#pragma unroll
    for (int i = 0; i < 4; ++i) {
        long f = fbase + t + 256 * i;
        float4 v;
        if (f < fmax) v = A4[f];
        else { v.x = 0.f; v.y = 0.f; v.z = 0.f; v.w = 0.f; }
        Xl4[t + 256 * i] = v;
    }
    __syncthreads();
    int rg = t >> 4, cg = t & 15;
    float a00 = 0.f, a01 = 0.f, a02 = 0.f, a03 = 0.f;
    float a10 = 0.f, a11 = 0.f, a12 = 0.f, a13 = 0.f;
    float a20 = 0.f, a21 = 0.f, a22 = 0.f, a23 = 0.f;
    float a30 = 0.f, a31 = 0.f, a32 = 0.f, a33 = 0.f;
#pragma unroll 4
    for (int k4 = 0; k4 < 16; ++k4) {
        float4 w0 = Wl4[(4 * k4 + 0) * 16 + cg];
        float4 w1 = Wl4[(4 * k4 + 1) * 16 + cg];
        float4 w2 = Wl4[(4 * k4 + 2) * 16 + cg];
        float4 w3 = Wl4[(4 * k4 + 3) * 16 + cg];
        float4 x0 = Xl4[(4 * rg + 0) * 16 + k4];
        float4 x1 = Xl4[(4 * rg + 1) * 16 + k4];
        float4 x2 = Xl4[(4 * rg + 2) * 16 + k4];
        float4 x3 = Xl4[(4 * rg + 3) * 16 + k4];
        a00 += x0.x * w0.x + x0.y * w1.x + x0.z * w2.x + x0.w * w3.x;
        a01 += x0.x * w0.y + x0.y * w1.y + x0.z * w2.y + x0.w * w3.y;
        a02 += x0.x * w0.z + x0.y * w1.z + x0.z * w2.z + x0.w * w3.z;
        a03 += x0.x * w0.w + x0.y * w1.w + x0.z * w2.w + x0.w * w3.w;
        a10 += x1.x * w0.x + x1.y * w1.x + x1.z * w2.x + x1.w * w3.x;
        a11 += x1.x * w0.y + x1.y * w1.y + x1.z * w2.y + x1.w * w3.y;
        a12 += x1.x * w0.z + x1.y * w1.z + x1.z * w2.z + x1.w * w3.z;
        a13 += x1.x * w0.w + x1.y * w1.w + x1.z * w2.w + x1.w * w3.w;
        a20 += x2.x * w0.x + x2.y * w1.x + x2.z * w2.x + x2.w * w3.x;
        a21 += x2.x * w0.y + x2.y * w1.y + x2.z * w2.y + x2.w * w3.y;
        a22 += x2.x * w0.z + x2.y * w1.z + x2.z * w2.z + x2.w * w3.z;
        a23 += x2.x * w0.w + x2.y * w1.w + x2.z * w2.w + x2.w * w3.w;
        a30 += x3.x * w0.x + x3.y * w1.x + x3.z * w2.x + x3.w * w3.x;
        a31 += x3.x * w0.y + x3.y * w1.y + x3.z * w2.y + x3.w * w3.y;
        a32 += x3.x * w0.z + x3.y * w1.z + x3.z * w2.z + x3.w * w3.z;
        a33 += x3.x * w0.w + x3.y * w1.w + x3.z * w2.w + x3.w * w3.w;
    }
    int vb = blockIdx.x * 64 + rg * 4;
    int v;
    float s;
    unsigned long long u;
    v = vb + 0;
    if (v < n) {
        s = scale[v];
        u  = (unsigned long long)(((unsigned int)f32_to_bf16(s * a01) << 16) | (unsigned int)f32_to_bf16(s * a00));
        u |= (unsigned long long)(((unsigned int)f32_to_bf16(s * a03) << 16) | (unsigned int)f32_to_bf16(s * a02)) << 32;
        C[(long)v * 16 + cg] = u;
    }
    v = vb + 1;
    if (v < n) {
        s = scale[v];
        u  = (unsigned long long)(((unsigned int)f32_to_bf16(s * a11) << 16) | (unsigned int)f32_to_bf16(s * a10));
        u |= (unsigned long long)(((unsigned int)f32_to_bf16(s * a13) << 16) | (unsigned int)f32_to_bf16(s * a12)) << 32;
        C[(long)v * 16 + cg] = u;
    }
    v = vb + 2;
    if (v < n) {
        s = scale[v];
        u  = (unsigned long long)(((unsigned int)f32_to_bf16(s * a21) << 16) | (unsigned int)f32_to_bf16(s * a20));
        u |= (unsigned long long)(((unsigned int)f32_to_bf16(s * a23) << 16) | (unsigned int)f32_to_bf16(s * a22)) << 32;
        C[(long)v * 16 + cg] = u;
    }
    v = vb + 3;
    if (v < n) {
        s = scale[v];
        u  = (unsigned long long)(((unsigned int)f32_to_bf16(s * a31) << 16) | (unsigned int)f32_to_bf16(s * a30));
        u |= (unsigned long long)(((unsigned int)f32_to_bf16(s * a33) << 16) | (unsigned int)f32_to_bf16(s * a32)) << 32;
        C[(long)v * 16 + cg] = u;
    }
}

// ---- gather core (R10-proven): 2 edges per gather instruction ----
__device__ __forceinline__ float gather_row(const unsigned int* __restrict__ xp,
                                            const int* __restrict__ csr,
                                            int s0, int d0, int h, int p, int v) {
    float l0 = 0.f, l1 = 0.f, l2 = 0.f, l3 = 0.f;
    float h0 = 0.f, h1 = 0.f, h2 = 0.f, h3 = 0.f;
    int i = 0;
    for (; i + 8 <= d0; i += 8) {
        int j0 = csr[s0 + i + 0 + h];
        int j1 = csr[s0 + i + 2 + h];
        int j2 = csr[s0 + i + 4 + h];
        int j3 = csr[s0 + i + 6 + h];
        unsigned int u0 = xp[(long)j0 * 32 + p];
        unsigned int u1 = xp[(long)j1 * 32 + p];
        unsigned int u2 = xp[(long)j2 * 32 + p];
        unsigned int u3 = xp[(long)j3 * 32 + p];
        l0 += __uint_as_float(u0 << 16);  h0 += __uint_as_float(u0 & 0xFFFF0000u);
        l1 += __uint_as_float(u1 << 16);  h1 += __uint_as_float(u1 & 0xFFFF0000u);
        l2 += __uint_as_float(u2 << 16);  h2 += __uint_as_float(u2 & 0xFFFF0000u);
        l3 += __uint_as_float(u3 << 16);  h3 += __uint_as_float(u3 & 0xFFFF0000u);
    }
    for (; i + 2 <= d0; i += 2) {
        int j = csr[s0 + i + h];
        unsigned int u = xp[(long)j * 32 + p];
        l0 += __uint_as_float(u << 16);
        h0 += __uint_as_float(u & 0xFFFF0000u);
    }
    if (i < d0 && h == 0) {               // odd leftover edge: half-wave 0 only
        int j = csr[s0 + i];
        unsigned int u = xp[(long)j * 32 + p];
        l0 += __uint_as_float(u << 16);
        h0 += __uint_as_float(u & 0xFFFF0000u);
    }
    float al = (l0 + l1) + (l2 + l3);
    float ah = (h0 + h1) + (h2 + h3);
    al += __shfl_xor(al, 32);             // merge the two half-waves
    ah += __shfl_xor(ah, 32);
    unsigned int us = xp[(long)v * 32 + p];   // self loop
    al += __uint_as_float(us << 16);
    ah += __uint_as_float(us & 0xFFFF0000u);
    return h ? ah : al;
}

// ---- aggregation (layer 1): out[v,:] = relu( dinv[v]*gather + b ), f32 out ----
__global__ void agg_k(const unsigned int* __restrict__ xp, const float* __restrict__ dinv,
                      const int* __restrict__ start, const int* __restrict__ csr,
                      const float* __restrict__ bias, float* __restrict__ out, int n) {
    int t = threadIdx.x;
    int lane = t & 63;
    int h = lane >> 5;
    int p = lane & 31;
    int v = blockIdx.x * 4 + (t >> 6);
    if (v >= n) return;
    int s0 = start[v];
    int d0 = start[v + 1] - s0;
    float sum = gather_row(xp, csr, s0, d0, h, p, v);
    int d = 2 * p + h;
    float val = sum * dinv[v] + bias[d];
    out[(long)v * NDIM + d] = fmaxf(val, 0.f);
}

// ---- aggpool v4: chunk=4 nodes/wave, 32x replicated pooled accumulator ----
// Chain depth = waves/(64 graphs * 32 reps) ~ 12. Occupancy like agg_k.
__global__ void aggpool_k(const unsigned int* __restrict__ xp, const float* __restrict__ dinv,
                          const int* __restrict__ start, const int* __restrict__ csr,
                          const float* __restrict__ b2, const int* __restrict__ batch,
                          float* __restrict__ pooledR, int n) {
    int t = threadIdx.x;
    int lane = t & 63;
    int h = lane >> 5, p = lane & 31;
    int wid = blockIdx.x * 4 + (t >> 6);
    int v0 = wid * 4;
    if (v0 >= n) return;
    int v1 = min(v0 + 4, n);
    int d = 2 * p + h;
    float bias = b2[d];
    long rbase = (long)(wid & (NREP - 1)) * (NGRAPH * NDIM);   // replica slice
    int gcur = -1;
    float acc = 0.f;
    for (int v = v0; v < v1; ++v) {
        int g = batch[v];                         // wave-uniform broadcast load
        if (g != gcur) {
            if (gcur >= 0) atomicAdd(&pooledR[rbase + gcur * NDIM + d], acc);
            gcur = g;
            acc = 0.f;
        }
        int s0 = start[v];
        int d0 = start[v + 1] - s0;
        float sum = gather_row(xp, csr, s0, d0, h, p, v);
        acc += fmaxf(sum * dinv[v] + bias, 0.f);
    }
    if (gcur >= 0) atomicAdd(&pooledR[rbase + gcur * NDIM + d], acc);
}

// ---- fold the 32 pooled replicas ----
__global__ void reduce_k(const float* __restrict__ pooledR, float* __restrict__ pooled) {
    int t = blockIdx.x * 256 + threadIdx.x;
    if (t >= NGRAPH * NDIM) return;
    float s = 0.f;
    for (int r = 0; r < NREP; ++r) s += pooledR[(long)r * (NGRAPH * NDIM) + t];
    pooled[t] = s;
}

// ---- head: out[g,c] = (pooled[g,:]/max(cnt,1)) @ Wlin + blin ----
__global__ void final_k(const float* __restrict__ pooled, const int* __restrict__ gstart,
                        const int* __restrict__ gend,
                        const float* __restrict__ Wlin, const float* __restrict__ blin,
                        float* __restrict__ out, int nclass) {
    int t = blockIdx.x * blockDim.x + threadIdx.x;
    if (t >= NGRAPH * nclass) return;
    int g = t / nclass, c = t % nclass;
    float cnt = (float)(gend[g] - gstart[g]);
    float inv = 1.f / fmaxf(cnt, 1.f);
    float acc = 0.f;
    for (int j = 0; j < NDIM; ++j) acc += pooled[g * NDIM + j] * Wlin[j * nclass + c];
    out[t] = acc * inv + blin[c];
}

extern "C" void kernel_launch(void* const* d_in, const int* in_sizes, int n_in,
                              void* d_out, int out_size, void* d_ws, size_t ws_size,
                              hipStream_t stream) {
    const float* x     = (const float*)d_in[0];
    const int*   ei    = (const int*)d_in[1];
    const int*   batch = (const int*)d_in[2];
    const float* W1    = (const float*)d_in[3];
    const float* b1    = (const float*)d_in[4];
    const float* W2    = (const float*)d_in[5];
    const float* b2    = (const float*)d_in[6];
    const float* Wlin  = (const float*)d_in[7];
    const float* blin  = (const float*)d_in[8];
    float* out = (float*)d_out;

    const int N = in_sizes[0] / NDIM;        // 100000
    const int E = in_sizes[1] / 2;           // 1600000
    const int NCLASS = in_sizes[7] / NDIM;   // 10
    const int* src = ei;
    const int* dst = ei + E;
    const int NB   = (N + BNODES - 1) >> BSHIFT;        // 782 buckets (<=1024)
    const int NBLK = (E + ECHUNK - 1) / ECHUNK;         // 196 edge blocks (<=256)

    // ---- workspace carve-out (each 256B-aligned) ----
    size_t o = 0;
    char* wsp = (char*)d_ws;
    auto take = [&](size_t nbytes) -> void* {
        void* p = (void*)(wsp + o);
        o += (nbytes + 255) & ~(size_t)255;
        return p;
    };
    int*   gstart    = (int*)take(NGRAPH * 4);
    int*   gend      = (int*)take(NGRAPH * 4);
    float* pooledR   = (float*)take((size_t)NREP * NGRAPH * NDIM * 4);   // 512 KB
    size_t zero_bytes = o;                    // everything above must start at 0
    float* pooled    = (float*)take(NGRAPH * NDIM * 4);
    int*   cntmat   = (int*)take((size_t)NBLK * NB * 4);
    int*   basemat  = (int*)take((size_t)NBLK * NB * 4);
    int*   bucketTot   = (int*)take((size_t)NB * 4);
    int*   bucketStart = (int*)take((size_t)(NB + 1) * 4);
    float* dinv  = (float*)take((size_t)N * 4);
    int*   start = (int*)take((size_t)(N + 1) * 4);
    int*   csr   = (int*)take((size_t)E * 4);
    unsigned int* ebuf = (unsigned int*)take((size_t)E * 4);
    unsigned int* xws  = (unsigned int*)take((size_t)N * NDIM * 2);   // bf16 pairs
    float* h     = (float*)take((size_t)N * NDIM * 4);
    (void)ws_size;

    hipMemsetAsync(d_ws, 0, zero_bytes, stream);

    int rbl = (N + 3) / 4;                    // 4 nodes per block (agg)
    int gbl = (N + 63) / 64;                  // 64 rows per block (gemm v4)
    int pbl = (N + 15) / 16;                  // aggpool: 4 waves x 4 nodes per block

    // CSR build (deterministic two-pass binning, zero global atomics)
    bincnt_k<<<NBLK, 256, (size_t)NB * 4, stream>>>(dst, cntmat, E, NB);
    colscan_k<<<NB, 256, 0, stream>>>(cntmat, basemat, bucketTot, NBLK, NB);
    bscan_k<<<1, 1024, 0, stream>>>(bucketTot, bucketStart, start, NB, N, E);
    bscatter_k<<<NBLK, 256, (size_t)NB * 4, stream>>>(src, dst, bucketStart, basemat, ebuf, E, NB);
    fill2_k<<<NB, 256, 0, stream>>>(ebuf, bucketStart, batch, dinv, start, csr, gstart, gend, N);

    // layer 1
    gemm_k<<<gbl, 256, 0, stream>>>(x, W1, dinv, (unsigned long long*)xws, N);
    agg_k<<<rbl, 256, 0, stream>>>(xws, dinv, start, csr, b1, h, N);
    // layer 2
    gemm_k<<<gbl, 256, 0, stream>>>(h, W2, dinv, (unsigned long long*)xws, N);
    // fused layer2-agg + replicated register mean-pool
    aggpool_k<<<pbl, 256, 0, stream>>>(xws, dinv, start, csr, b2, batch, pooledR, N);
    reduce_k<<<(NGRAPH * NDIM + 255) / 256, 256, 0, stream>>>(pooledR, pooled);
    // head
    final_k<<<(NGRAPH * NCLASS + 255) / 256, 256, 0, stream>>>(pooled, gstart, gend, Wlin, blin, out, NCLASS);
}

// Round 17
// 276.778 us; speedup vs baseline: 1.4696x; 1.0679x over previous
//
#include <hip/hip_runtime.h>
#include <hip/hip_bf16.h>

// GCN: h1 = relu(Â (x W1) + b1); h2 = relu(Â (h1 W2) + b2);
// out = mean_pool(h2, batch) @ Wlin + blin,  Â = D^-1/2 (A+I) D^-1/2
//
// R5/R6: bucketed CSR build, deterministic two-pass, zero global atomics.
// R7: xws bf16 -> agg row gather 128 B.
// R8/R9 LESSON: sub-dword per-lane global stores defeat L2 write-merge.
// R10: agg v2 -- 2 edges per gather instr (latency-bound, not byte-bound).
// R12 LESSON: multi-NODE gather unroll spills. One node context per wave.
// R14 LESSON: same-address atomic chains ~125 ns/link; keep <= ~100.
// R15/R16: replicated pooled accumulators decouple chain depth from
//     occupancy (chunk=4, 32 replicas, reduce_k fold). 295 us.
// R17: gather MLP x2 -- 16-edge main tier issues 8 independent row-gathers
//     per half-wave (one node context, named scalars; VGPR ~40, no spill);
//     tiers 8/4/2/1 for remainders. agg was latency-bound at 4 in flight.

#define NDIM 64
#define NGRAPH 64
#define NREP 32
#define BSHIFT 7                      // 128 nodes per bucket
#define BNODES 128
#define ECHUNK 8192                   // edges per block in bincnt/bscatter (32/thread)

__device__ __forceinline__ unsigned short f32_to_bf16(float f) {
    unsigned int u = __float_as_uint(f);
    unsigned int r = 0x7FFFu + ((u >> 16) & 1u);   // round-to-nearest-even
    return (unsigned short)((u + r) >> 16);
}

// ---- pass 1: per-(block,bucket) edge counts via LDS histogram ----
__global__ void bincnt_k(const int* __restrict__ dst, int* __restrict__ cntmat,
                         int e, int nb) {
    extern __shared__ int hist[];
    int t = threadIdx.x;
    for (int i = t; i < nb; i += 256) hist[i] = 0;
    __syncthreads();
    int base = blockIdx.x * ECHUNK + t;
#pragma unroll
    for (int k = 0; k < 32; ++k) {
        int i = base + k * 256;
        if (i < e) atomicAdd(&hist[dst[i] >> BSHIFT], 1);   // LDS atomic
    }
    __syncthreads();
    long row = (long)blockIdx.x * nb;
    for (int i = t; i < nb; i += 256) cntmat[row + i] = hist[i];
}

// ---- pass 2: per-bucket exclusive scan across blocks (one block per bucket) ----
__global__ void colscan_k(const int* __restrict__ cntmat, int* __restrict__ basemat,
                          int* __restrict__ bucketTot, int nblk, int nb) {
    __shared__ int s[256];
    int b = blockIdx.x;
    int t = threadIdx.x;
    int v = (t < nblk) ? cntmat[(long)t * nb + b] : 0;
    s[t] = v;
    __syncthreads();
    for (int off = 1; off < 256; off <<= 1) {
        int tmp = (t >= off) ? s[t - off] : 0;
        __syncthreads();
        s[t] += tmp;
        __syncthreads();
    }
    if (t < nblk) basemat[(long)t * nb + b] = s[t] - v;   // exclusive within column
    if (t == 255) bucketTot[b] = s[255];
}

// ---- pass 3: exclusive scan of bucket totals (single block, nb<=1024) ----
__global__ void bscan_k(const int* __restrict__ bucketTot, int* __restrict__ bucketStart,
                        int* __restrict__ start, int nb, int n, int e) {
    __shared__ int s[1024];
    int t = threadIdx.x;
    int v = (t < nb) ? bucketTot[t] : 0;
    s[t] = v;
    __syncthreads();
    for (int off = 1; off < 1024; off <<= 1) {
        int tmp = (t >= off) ? s[t - off] : 0;
        __syncthreads();
        s[t] += tmp;
        __syncthreads();
    }
    if (t < nb) bucketStart[t + 1] = s[t];
    if (t == 0) { bucketStart[0] = 0; start[n] = e; }   // CSR sentinel
}

// ---- pass 4: scatter packed (dst_local<<25 | src) via block-private LDS cursors ----
__global__ void bscatter_k(const int* __restrict__ src, const int* __restrict__ dst,
                           const int* __restrict__ bucketStart,
                           const int* __restrict__ basemat,
                           unsigned int* __restrict__ ebuf, int e, int nb) {
    extern __shared__ int cur[];
    int t = threadIdx.x;
    long row = (long)blockIdx.x * nb;
    for (int i = t; i < nb; i += 256) cur[i] = bucketStart[i] + basemat[row + i];
    __syncthreads();
    int base = blockIdx.x * ECHUNK + t;
#pragma unroll
    for (int k = 0; k < 32; ++k) {
        int i = base + k * 256;
        if (i < e) {
            int d = dst[i];
            int b = d >> BSHIFT;
            int pos = atomicAdd(&cur[b], 1);               // LDS atomic, block-private
            ebuf[pos] = ((unsigned)(d & (BNODES - 1)) << 25) | (unsigned)src[i];
        }
    }
}

// ---- pass 5: one block per bucket -> dst-ordered CSR slice, dinv, graph ranges ----
__global__ void fill2_k(const unsigned int* __restrict__ ebuf,
                        const int* __restrict__ bucketStart,
                        const int* __restrict__ batch, float* __restrict__ dinv,
                        int* __restrict__ start, int* __restrict__ csr,
                        int* __restrict__ gstart, int* __restrict__ gend, int n) {
    __shared__ int scnt[BNODES], sincl[BNODES], scur[BNODES];
    int t = threadIdx.x;
    int b = blockIdx.x;
    int node0 = b << BSHIFT;
    int nNodes = min(BNODES, n - node0);
    if (t < BNODES) scnt[t] = 0;
    int e0 = bucketStart[b], e1 = bucketStart[b + 1];
    __syncthreads();
    for (int i = e0 + t; i < e1; i += 256)
        atomicAdd(&scnt[ebuf[i] >> 25], 1);
    __syncthreads();
    int val = (t < BNODES) ? scnt[t] : 0;
    if (t < BNODES) sincl[t] = val;
    __syncthreads();
    for (int off = 1; off < BNODES; off <<= 1) {
        int tmp = (t >= off && t < BNODES) ? sincl[t - off] : 0;
        __syncthreads();
        if (t < BNODES) sincl[t] += tmp;
        __syncthreads();
    }
    if (t < nNodes) {
        int v = node0 + t;
        int st = e0 + sincl[t] - val;     // exclusive within bucket
        start[v] = st;
        scur[t] = st;
        dinv[v] = rsqrtf((float)(val + 1));
        int g = batch[v];                 // sorted-batch boundary detection
        if (v == 0 || batch[v - 1] != g) gstart[g] = v;
        if (v == n - 1 || batch[v + 1] != g) gend[g] = v + 1;
    }
    __syncthreads();
    for (int i = e0 + t; i < e1; i += 256) {
        unsigned rec = ebuf[i];
        int pos = atomicAdd(&scur[rec >> 25], 1);
        csr[pos] = (int)(rec & 0x1FFFFFFu);   // scatter within L2-local 8 KB slice
    }
}

// ---- dense GEMM v4  C[n,64](bf16 pairs) = scale[row] * (A[n,64] @ W[64,64]) ----
__global__ void gemm_k(const float* __restrict__ A, const float* __restrict__ W,
                       const float* __restrict__ scale,
                       unsigned long long* __restrict__ C, int n) {
    __shared__ float4 Wl4[64 * 16];   // 16 KB: W[k][4c..4c+3]
    __shared__ float4 Xl4[64 * 16];   // 16 KB: X[r][4k..4k+3]
    int t = threadIdx.x;
    const float4* W4 = (const float4*)W;
#pragma unroll
    for (int i = 0; i < 4; ++i) Wl4[t + 256 * i] = W4[t + 256 * i];
    const float4* A4 = (const float4*)A;
    long fbase = (long)blockIdx.x * 1024;
    long fmax  = (long)n * 16;
#pragma unroll
    for (int i = 0; i < 4; ++i) {
        long f = fbase + t + 256 * i;
        float4 v;
        if (f < fmax) v = A4[f];
        else { v.x = 0.f; v.y = 0.f; v.z = 0.f; v.w = 0.f; }
        Xl4[t + 256 * i] = v;
    }
    __syncthreads();
    int rg = t >> 4, cg = t & 15;
    float a00 = 0.f, a01 = 0.f, a02 = 0.f, a03 = 0.f;
    float a10 = 0.f, a11 = 0.f, a12 = 0.f, a13 = 0.f;
    float a20 = 0.f, a21 = 0.f, a22 = 0.f, a23 = 0.f;
    float a30 = 0.f, a31 = 0.f, a32 = 0.f, a33 = 0.f;
#pragma unroll 4
    for (int k4 = 0; k4 < 16; ++k4) {
        float4 w0 = Wl4[(4 * k4 + 0) * 16 + cg];
        float4 w1 = Wl4[(4 * k4 + 1) * 16 + cg];
        float4 w2 = Wl4[(4 * k4 + 2) * 16 + cg];
        float4 w3 = Wl4[(4 * k4 + 3) * 16 + cg];
        float4 x0 = Xl4[(4 * rg + 0) * 16 + k4];
        float4 x1 = Xl4[(4 * rg + 1) * 16 + k4];
        float4 x2 = Xl4[(4 * rg + 2) * 16 + k4];
        float4 x3 = Xl4[(4 * rg + 3) * 16 + k4];
        a00 += x0.x * w0.x + x0.y * w1.x + x0.z * w2.x + x0.w * w3.x;
        a01 += x0.x * w0.y + x0.y * w1.y + x0.z * w2.y + x0.w * w3.y;
        a02 += x0.x * w0.z + x0.y * w1.z + x0.z * w2.z + x0.w * w3.z;
        a03 += x0.x * w0.w + x0.y * w1.w + x0.z * w2.w + x0.w * w3.w;
        a10 += x1.x * w0.x + x1.y * w1.x + x1.z * w2.x + x1.w * w3.x;
        a11 += x1.x * w0.y + x1.y * w1.y + x1.z * w2.y + x1.w * w3.y;
        a12 += x1.x * w0.z + x1.y * w1.z + x1.z * w2.z + x1.w * w3.z;
        a13 += x1.x * w0.w + x1.y * w1.w + x1.z * w2.w + x1.w * w3.w;
        a20 += x2.x * w0.x + x2.y * w1.x + x2.z * w2.x + x2.w * w3.x;
        a21 += x2.x * w0.y + x2.y * w1.y + x2.z * w2.y + x2.w * w3.y;
        a22 += x2.x * w0.z + x2.y * w1.z + x2.z * w2.z + x2.w * w3.z;
        a23 += x2.x * w0.w + x2.y * w1.w + x2.z * w2.w + x2.w * w3.w;
        a30 += x3.x * w0.x + x3.y * w1.x + x3.z * w2.x + x3.w * w3.x;
        a31 += x3.x * w0.y + x3.y * w1.y + x3.z * w2.y + x3.w * w3.y;
        a32 += x3.x * w0.z + x3.y * w1.z + x3.z * w2.z + x3.w * w3.z;
        a33 += x3.x * w0.w + x3.y * w1.w + x3.z * w2.w + x3.w * w3.w;
    }
    int vb = blockIdx.x * 64 + rg * 4;
    int v;
    float s;
    unsigned long long u;
    v = vb + 0;
    if (v < n) {
        s = scale[v];
        u  = (unsigned long long)(((unsigned int)f32_to_bf16(s * a01) << 16) | (unsigned int)f32_to_bf16(s * a00));
        u |= (unsigned long long)(((unsigned int)f32_to_bf16(s * a03) << 16) | (unsigned int)f32_to_bf16(s * a02)) << 32;
        C[(long)v * 16 + cg] = u;
    }
    v = vb + 1;
    if (v < n) {
        s = scale[v];
        u  = (unsigned long long)(((unsigned int)f32_to_bf16(s * a11) << 16) | (unsigned int)f32_to_bf16(s * a10));
        u |= (unsigned long long)(((unsigned int)f32_to_bf16(s * a13) << 16) | (unsigned int)f32_to_bf16(s * a12)) << 32;
        C[(long)v * 16 + cg] = u;
    }
    v = vb + 2;
    if (v < n) {
        s = scale[v];
        u  = (unsigned long long)(((unsigned int)f32_to_bf16(s * a21) << 16) | (unsigned int)f32_to_bf16(s * a20));
        u |= (unsigned long long)(((unsigned int)f32_to_bf16(s * a23) << 16) | (unsigned int)f32_to_bf16(s * a22)) << 32;
        C[(long)v * 16 + cg] = u;
    }
    v = vb + 3;
    if (v < n) {
        s = scale[v];
        u  = (unsigned long long)(((unsigned int)f32_to_bf16(s * a31) << 16) | (unsigned int)f32_to_bf16(s * a30));
        u |= (unsigned long long)(((unsigned int)f32_to_bf16(s * a33) << 16) | (unsigned int)f32_to_bf16(s * a32)) << 32;
        C[(long)v * 16 + cg] = u;
    }
}

// ---- gather core v3 (R17): tiers 16/8/4/2/1 edges; up to 8 gathers in
// flight per half-wave. ONE node context, named scalars only (R12 lesson).
// lane covers dim pair p=lane&31 via dword (2 bf16); half-wave h=lane>>5
// handles edges i+h. Returns value for dim d = 2p+h (self-loop included).
__device__ __forceinline__ float gather_row(const unsigned int* __restrict__ xp,
                                            const int* __restrict__ csr,
                                            int s0, int d0, int h, int p, int v) {
    float l0 = 0.f, l1 = 0.f, l2 = 0.f, l3 = 0.f;
    float h0 = 0.f, h1 = 0.f, h2 = 0.f, h3 = 0.f;
    int i = 0;
    for (; i + 16 <= d0; i += 16) {       // 8 gathers in flight
        int j0 = csr[s0 + i +  0 + h];
        int j1 = csr[s0 + i +  2 + h];
        int j2 = csr[s0 + i +  4 + h];
        int j3 = csr[s0 + i +  6 + h];
        int j4 = csr[s0 + i +  8 + h];
        int j5 = csr[s0 + i + 10 + h];
        int j6 = csr[s0 + i + 12 + h];
        int j7 = csr[s0 + i + 14 + h];
        unsigned int u0 = xp[(long)j0 * 32 + p];
        unsigned int u1 = xp[(long)j1 * 32 + p];
        unsigned int u2 = xp[(long)j2 * 32 + p];
        unsigned int u3 = xp[(long)j3 * 32 + p];
        unsigned int u4 = xp[(long)j4 * 32 + p];
        unsigned int u5 = xp[(long)j5 * 32 + p];
        unsigned int u6 = xp[(long)j6 * 32 + p];
        unsigned int u7 = xp[(long)j7 * 32 + p];
        l0 += __uint_as_float(u0 << 16);  h0 += __uint_as_float(u0 & 0xFFFF0000u);
        l1 += __uint_as_float(u1 << 16);  h1 += __uint_as_float(u1 & 0xFFFF0000u);
        l2 += __uint_as_float(u2 << 16);  h2 += __uint_as_float(u2 & 0xFFFF0000u);
        l3 += __uint_as_float(u3 << 16);  h3 += __uint_as_float(u3 & 0xFFFF0000u);
        l0 += __uint_as_float(u4 << 16);  h0 += __uint_as_float(u4 & 0xFFFF0000u);
        l1 += __uint_as_float(u5 << 16);  h1 += __uint_as_float(u5 & 0xFFFF0000u);
        l2 += __uint_as_float(u6 << 16);  h2 += __uint_as_float(u6 & 0xFFFF0000u);
        l3 += __uint_as_float(u7 << 16);  h3 += __uint_as_float(u7 & 0xFFFF0000u);
    }
    for (; i + 8 <= d0; i += 8) {         // 4 gathers in flight
        int j0 = csr[s0 + i + 0 + h];
        int j1 = csr[s0 + i + 2 + h];
        int j2 = csr[s0 + i + 4 + h];
        int j3 = csr[s0 + i + 6 + h];
        unsigned int u0 = xp[(long)j0 * 32 + p];
        unsigned int u1 = xp[(long)j1 * 32 + p];
        unsigned int u2 = xp[(long)j2 * 32 + p];
        unsigned int u3 = xp[(long)j3 * 32 + p];
        l0 += __uint_as_float(u0 << 16);  h0 += __uint_as_float(u0 & 0xFFFF0000u);
        l1 += __uint_as_float(u1 << 16);  h1 += __uint_as_float(u1 & 0xFFFF0000u);
        l2 += __uint_as_float(u2 << 16);  h2 += __uint_as_float(u2 & 0xFFFF0000u);
        l3 += __uint_as_float(u3 << 16);  h3 += __uint_as_float(u3 & 0xFFFF0000u);
    }
    for (; i + 4 <= d0; i += 4) {         // 2 gathers in flight
        int j0 = csr[s0 + i + 0 + h];
        int j1 = csr[s0 + i + 2 + h];
        unsigned int u0 = xp[(long)j0 * 32 + p];
        unsigned int u1 = xp[(long)j1 * 32 + p];
        l0 += __uint_as_float(u0 << 16);  h0 += __uint_as_float(u0 & 0xFFFF0000u);
        l1 += __uint_as_float(u1 << 16);  h1 += __uint_as_float(u1 & 0xFFFF0000u);
    }
    for (; i + 2 <= d0; i += 2) {
        int j = csr[s0 + i + h];
        unsigned int u = xp[(long)j * 32 + p];
        l0 += __uint_as_float(u << 16);
        h0 += __uint_as_float(u & 0xFFFF0000u);
    }
    if (i < d0 && h == 0) {               // odd leftover edge: half-wave 0 only
        int j = csr[s0 + i];
        unsigned int u = xp[(long)j * 32 + p];
        l0 += __uint_as_float(u << 16);
        h0 += __uint_as_float(u & 0xFFFF0000u);
    }
    float al = (l0 + l1) + (l2 + l3);
    float ah = (h0 + h1) + (h2 + h3);
    al += __shfl_xor(al, 32);             // merge the two half-waves
    ah += __shfl_xor(ah, 32);
    unsigned int us = xp[(long)v * 32 + p];   // self loop
    al += __uint_as_float(us << 16);
    ah += __uint_as_float(us & 0xFFFF0000u);
    return h ? ah : al;
}

// ---- aggregation (layer 1): out[v,:] = relu( dinv[v]*gather + b ), f32 out ----
__global__ void agg_k(const unsigned int* __restrict__ xp, const float* __restrict__ dinv,
                      const int* __restrict__ start, const int* __restrict__ csr,
                      const float* __restrict__ bias, float* __restrict__ out, int n) {
    int t = threadIdx.x;
    int lane = t & 63;
    int h = lane >> 5;
    int p = lane & 31;
    int v = blockIdx.x * 4 + (t >> 6);
    if (v >= n) return;
    int s0 = start[v];
    int d0 = start[v + 1] - s0;
    float sum = gather_row(xp, csr, s0, d0, h, p, v);
    int d = 2 * p + h;
    float val = sum * dinv[v] + bias[d];
    out[(long)v * NDIM + d] = fmaxf(val, 0.f);
}

// ---- aggpool v4: chunk=4 nodes/wave, 32x replicated pooled accumulator ----
__global__ void aggpool_k(const unsigned int* __restrict__ xp, const float* __restrict__ dinv,
                          const int* __restrict__ start, const int* __restrict__ csr,
                          const float* __restrict__ b2, const int* __restrict__ batch,
                          float* __restrict__ pooledR, int n) {
    int t = threadIdx.x;
    int lane = t & 63;
    int h = lane >> 5, p = lane & 31;
    int wid = blockIdx.x * 4 + (t >> 6);
    int v0 = wid * 4;
    if (v0 >= n) return;
    int v1 = min(v0 + 4, n);
    int d = 2 * p + h;
    float bias = b2[d];
    long rbase = (long)(wid & (NREP - 1)) * (NGRAPH * NDIM);   // replica slice
    int gcur = -1;
    float acc = 0.f;
    for (int v = v0; v < v1; ++v) {
        int g = batch[v];                         // wave-uniform broadcast load
        if (g != gcur) {
            if (gcur >= 0) atomicAdd(&pooledR[rbase + gcur * NDIM + d], acc);
            gcur = g;
            acc = 0.f;
        }
        int s0 = start[v];
        int d0 = start[v + 1] - s0;
        float sum = gather_row(xp, csr, s0, d0, h, p, v);
        acc += fmaxf(sum * dinv[v] + bias, 0.f);
    }
    if (gcur >= 0) atomicAdd(&pooledR[rbase + gcur * NDIM + d], acc);
}

// ---- fold the 32 pooled replicas ----
__global__ void reduce_k(const float* __restrict__ pooledR, float* __restrict__ pooled) {
    int t = blockIdx.x * 256 + threadIdx.x;
    if (t >= NGRAPH * NDIM) return;
    float s = 0.f;
    for (int r = 0; r < NREP; ++r) s += pooledR[(long)r * (NGRAPH * NDIM) + t];
    pooled[t] = s;
}

// ---- head: out[g,c] = (pooled[g,:]/max(cnt,1)) @ Wlin + blin ----
__global__ void final_k(const float* __restrict__ pooled, const int* __restrict__ gstart,
                        const int* __restrict__ gend,
                        const float* __restrict__ Wlin, const float* __restrict__ blin,
                        float* __restrict__ out, int nclass) {
    int t = blockIdx.x * blockDim.x + threadIdx.x;
    if (t >= NGRAPH * nclass) return;
    int g = t / nclass, c = t % nclass;
    float cnt = (float)(gend[g] - gstart[g]);
    float inv = 1.f / fmaxf(cnt, 1.f);
    float acc = 0.f;
    for (int j = 0; j < NDIM; ++j) acc += pooled[g * NDIM + j] * Wlin[j * nclass + c];
    out[t] = acc * inv + blin[c];
}

extern "C" void kernel_launch(void* const* d_in, const int* in_sizes, int n_in,
                              void* d_out, int out_size, void* d_ws, size_t ws_size,
                              hipStream_t stream) {
    const float* x     = (const float*)d_in[0];
    const int*   ei    = (const int*)d_in[1];
    const int*   batch = (const int*)d_in[2];
    const float* W1    = (const float*)d_in[3];
    const float* b1    = (const float*)d_in[4];
    const float* W2    = (const float*)d_in[5];
    const float* b2    = (const float*)d_in[6];
    const float* Wlin  = (const float*)d_in[7];
    const float* blin  = (const float*)d_in[8];
    float* out = (float*)d_out;

    const int N = in_sizes[0] / NDIM;        // 100000
    const int E = in_sizes[1] / 2;           // 1600000
    const int NCLASS = in_sizes[7] / NDIM;   // 10
    const int* src = ei;
    const int* dst = ei + E;
    const int NB   = (N + BNODES - 1) >> BSHIFT;        // 782 buckets (<=1024)
    const int NBLK = (E + ECHUNK - 1) / ECHUNK;         // 196 edge blocks (<=256)

    // ---- workspace carve-out (each 256B-aligned) ----
    size_t o = 0;
    char* wsp = (char*)d_ws;
    auto take = [&](size_t nbytes) -> void* {
        void* p = (void*)(wsp + o);
        o += (nbytes + 255) & ~(size_t)255;
        return p;
    };
    int*   gstart    = (int*)take(NGRAPH * 4);
    int*   gend      = (int*)take(NGRAPH * 4);
    float* pooledR   = (float*)take((size_t)NREP * NGRAPH * NDIM * 4);   // 512 KB
    size_t zero_bytes = o;                    // everything above must start at 0
    float* pooled    = (float*)take(NGRAPH * NDIM * 4);
    int*   cntmat   = (int*)take((size_t)NBLK * NB * 4);
    int*   basemat  = (int*)take((size_t)NBLK * NB * 4);
    int*   bucketTot   = (int*)take((size_t)NB * 4);
    int*   bucketStart = (int*)take((size_t)(NB + 1) * 4);
    float* dinv  = (float*)take((size_t)N * 4);
    int*   start = (int*)take((size_t)(N + 1) * 4);
    int*   csr   = (int*)take((size_t)E * 4);
    unsigned int* ebuf = (unsigned int*)take((size_t)E * 4);
    unsigned int* xws  = (unsigned int*)take((size_t)N * NDIM * 2);   // bf16 pairs
    float* h     = (float*)take((size_t)N * NDIM * 4);
    (void)ws_size;

    hipMemsetAsync(d_ws, 0, zero_bytes, stream);

    int rbl = (N + 3) / 4;                    // 4 nodes per block (agg)
    int gbl = (N + 63) / 64;                  // 64 rows per block (gemm v4)
    int pbl = (N + 15) / 16;                  // aggpool: 4 waves x 4 nodes per block

    // CSR build (deterministic two-pass binning, zero global atomics)
    bincnt_k<<<NBLK, 256, (size_t)NB * 4, stream>>>(dst, cntmat, E, NB);
    colscan_k<<<NB, 256, 0, stream>>>(cntmat, basemat, bucketTot, NBLK, NB);
    bscan_k<<<1, 1024, 0, stream>>>(bucketTot, bucketStart, start, NB, N, E);
    bscatter_k<<<NBLK, 256, (size_t)NB * 4, stream>>>(src, dst, bucketStart, basemat, ebuf, E, NB);
    fill2_k<<<NB, 256, 0, stream>>>(ebuf, bucketStart, batch, dinv, start, csr, gstart, gend, N);

    // layer 1
    gemm_k<<<gbl, 256, 0, stream>>>(x, W1, dinv, (unsigned long long*)xws, N);
    agg_k<<<rbl, 256, 0, stream>>>(xws, dinv, start, csr, b1, h, N);
    // layer 2
    gemm_k<<<gbl, 256, 0, stream>>>(h, W2, dinv, (unsigned long long*)xws, N);
    // fused layer2-agg + replicated register mean-pool
    aggpool_k<<<pbl, 256, 0, stream>>>(xws, dinv, start, csr, b2, batch, pooledR, N);
    reduce_k<<<(NGRAPH * NDIM + 255) / 256, 256, 0, stream>>>(pooledR, pooled);
    // head
    final_k<<<(NGRAPH * NCLASS + 255) / 256, 256, 0, stream>>>(pooled, gstart, gend, Wlin, blin, out, NCLASS);
}